// Round 1
// baseline (31123.953 us; speedup 1.0000x reference)
//
#include <hip/hip_runtime.h>

#define B_   16
#define T_   1600
#define D_   512
#define U_   1024
#define G_   4096           // 4*U
#define NWG  256            // 128 per direction, 1 per CU
#define TPB  256
#define KTOT 1536           // D + U
#define APAD 1544           // KTOT + 8 pad (ushort elems) -> breaks LDS bank aliasing
#define ROWB (APAD*2)       // 3088 bytes per row

typedef __attribute__((ext_vector_type(8))) __bf16 bf16x8;
typedef __attribute__((ext_vector_type(4))) float  f32x4;
typedef __attribute__((ext_vector_type(4))) unsigned short us4v;
typedef __attribute__((ext_vector_type(8))) unsigned short us8v;

__device__ __forceinline__ unsigned short f2bf(float f) {
  unsigned u = __builtin_bit_cast(unsigned, f);
  u += 0x7FFFu + ((u >> 16) & 1u);          // round-to-nearest-even
  return (unsigned short)(u >> 16);
}
__device__ __forceinline__ float sigm(float x){ return 1.f / (1.f + __expf(-x)); }
__device__ __forceinline__ float tanh_(float x){ return 1.f - 2.f / (__expf(2.f*x) + 1.f); }

extern "C" __global__ void __launch_bounds__(TPB, 1)
bilstm_kernel(const float* __restrict__ x, const int* __restrict__ xlen,
              const float* __restrict__ kf, const float* __restrict__ rkf, const float* __restrict__ bf_,
              const float* __restrict__ kb, const float* __restrict__ rkb, const float* __restrict__ bb_,
              float* __restrict__ out, unsigned* __restrict__ sync_ctr,
              unsigned short* __restrict__ hbuf)
{
  extern __shared__ char smem[];
  char*  Wb     = smem;                       // [32][APAD] ushort (bf16 weights, col-major-N: W[col][k])
  char*  Ab     = smem + 32*ROWB;             // [16][APAD] ushort (A = [batch][x|h] bf16)
  float* gates  = (float*)(smem + 48*ROWB);   // [2 khalf][16][32] partial gate sums
  float* bias_s = gates + 1024;               // [32]
  float* c_s    = bias_s + 32;                // [16][8] persistent cell state

  const int tid = threadIdx.x;
  const int wg  = blockIdx.x;
  const int dir = wg >> 7;          // 0 = fwd, 1 = bwd
  const int wsl = wg & 127;
  const int u0  = wsl << 3;         // first of 8 owned units

  if (wg == 0 && tid < B_)          // output 1: x_len passthrough (read as float chunk)
    out[(size_t)B_*T_*2*U_ + tid] = (float)xlen[tid];

  const float* Km = dir ? kb  : kf;
  const float* Rm = dir ? rkb : rkf;
  const float* Bv = dir ? bb_ : bf_;

  // ---- one-time: stage weight slice [1536][32] -> LDS bf16, W[col][k] ----
  for (int i = tid; i < KTOT*32; i += TPB) {
    int k = i >> 5, c = i & 31;
    int gc = ((c >> 3) << 10) + u0 + (c & 7);   // gate (c>>3)*U + unit
    float wv = (k < D_) ? Km[(size_t)k*G_ + gc] : Rm[(size_t)(k-D_)*G_ + gc];
    *(unsigned short*)(Wb + c*ROWB + (k << 1)) = f2bf(wv);
  }
  if (tid < 32)  bias_s[tid] = Bv[((tid >> 3) << 10) + u0 + (tid & 7)];
  if (tid < 128) c_s[tid] = 0.f;
  __syncthreads();

  const int w = tid >> 6, l = tid & 63;
  const int ntile = w & 1, khalf = w >> 1;
  const char* Arow = Ab + (l & 15)*ROWB + ((l >> 4) << 4);               // A-frag: row=l&15, k-off=(l>>4)*8
  const char* Brow = Wb + (ntile*16 + (l & 15))*ROWB + ((l >> 4) << 4);  // B-frag: col=l&15 (+ntile*16)
  float* gp = gates + khalf*512;
  const int drow0 = (l >> 4) << 2, dcol = ntile*16 + (l & 15);

  for (int t = 0; t < T_; ++t) {
    const int tg = dir ? (T_ - 1 - t) : t;
    const int pread = t & 1, pwrite = pread ^ 1;

    // stage x[:,tg,:] fp32 -> bf16 into A[:,0:512]
    {
      const float* xt = x + (size_t)tg * D_;
      for (int j = tid; j < 2048; j += TPB) {
        int b = j >> 7, k4 = (j & 127) << 2;
        const float4 v = *(const float4*)(xt + (size_t)b*T_*D_ + k4);
        us4v o4; o4[0]=f2bf(v.x); o4[1]=f2bf(v.y); o4[2]=f2bf(v.z); o4[3]=f2bf(v.w);
        *(us4v*)(Ab + b*ROWB + (k4 << 1)) = o4;
      }
    }
    // stage h_{t-1} (bf16) into A[:,512:1536]
    if (t > 0) {
      const unsigned short* hsrc = hbuf + (((size_t)pread*2 + dir) << 14);
      for (int j = tid; j < 2048; j += TPB) {
        int b = j >> 7, u8 = (j & 127) << 3;
        us8v v = *(const us8v*)(hsrc + (b << 10) + u8);
        *(us8v*)(Ab + b*ROWB + ((D_ + u8) << 1)) = v;
      }
    }
    __syncthreads();

    // MFMA: gates[16 batch x 32 cols] += A[16 x K] * W[K x 32]
    {
      f32x4 acc = {0.f,0.f,0.f,0.f};
      const int half = (t == 0) ? 8 : 24;      // t=0: h==0, only x-projection (K=512)
      const int ks0 = khalf * half, ks1 = ks0 + half;
      for (int ks = ks0; ks < ks1; ++ks) {
        bf16x8 a  = *(const bf16x8*)(Arow + (ks << 6));
        bf16x8 bv = *(const bf16x8*)(Brow + (ks << 6));
        acc = __builtin_amdgcn_mfma_f32_16x16x32_bf16(a, bv, acc, 0, 0, 0);
      }
      #pragma unroll
      for (int j = 0; j < 4; ++j) gp[(drow0 + j)*32 + dcol] = acc[j];
    }
    __syncthreads();

    // epilogue: one thread per (batch, unit)
    if (tid < 128) {
      int b = tid >> 3, uo = tid & 7;
      const float* g0 = gates + b*32 + uo;
      float gi = g0[0]  + g0[512] + bias_s[uo];
      float gf = g0[8]  + g0[520] + bias_s[8 + uo];
      float gz = g0[16] + g0[528] + bias_s[16 + uo];
      float go = g0[24] + g0[536] + bias_s[24 + uo];
      float cn = sigm(gf)*c_s[tid] + sigm(gi)*tanh_(gz);
      c_s[tid] = cn;
      float h = sigm(go)*tanh_(cn);
      out[((size_t)b*T_ + tg)*(2*U_) + (dir << 10) + u0 + uo] = h;
      hbuf[(((size_t)pwrite*2 + dir) << 14) + (b << 10) + u0 + uo] = f2bf(h);
    }

    // grid barrier (device-scope, monotonic counter)
    if (t < T_ - 1) {
      __syncthreads();
      if (tid == 0) {
        __hip_atomic_fetch_add(sync_ctr, 1u, __ATOMIC_RELEASE, __HIP_MEMORY_SCOPE_AGENT);
        const unsigned tgt = (unsigned)(t + 1) * NWG;
        long long guard = 0;
        while (__hip_atomic_load(sync_ctr, __ATOMIC_RELAXED, __HIP_MEMORY_SCOPE_AGENT) < tgt) {
          __builtin_amdgcn_s_sleep(1);
          if (++guard > (1LL << 24)) break;   // safety valve: never hang the harness
        }
        __builtin_amdgcn_fence(__ATOMIC_ACQUIRE, "agent");
      }
      __syncthreads();
    }
  }
}

extern "C" void kernel_launch(void* const* d_in, const int* in_sizes, int n_in,
                              void* d_out, int out_size, void* d_ws, size_t ws_size,
                              hipStream_t stream) {
  const float* x   = (const float*)d_in[0];
  const int*   xl  = (const int*)d_in[1];
  const float* kf  = (const float*)d_in[2];
  const float* rkf = (const float*)d_in[3];
  const float* bf_ = (const float*)d_in[4];
  const float* kb  = (const float*)d_in[5];
  const float* rkb = (const float*)d_in[6];
  const float* bb_ = (const float*)d_in[7];
  float* out = (float*)d_out;

  unsigned* ctr = (unsigned*)d_ws;
  unsigned short* hbuf = (unsigned short*)((char*)d_ws + 256);

  hipMemsetAsync(d_ws, 0, 256, stream);   // reset barrier counter every launch (graph-safe)

  const size_t smem = 48*(size_t)ROWB + 1024*4 + 32*4 + 128*4;  // 152,960 B
  bilstm_kernel<<<NWG, TPB, smem, stream>>>(x, xl, kf, rkf, bf_, kb, rkb, bb_, out, ctr, hbuf);
}

// Round 2
// 15740.723 us; speedup vs baseline: 1.9773x; 1.9773x over previous
//
#include <hip/hip_runtime.h>

#define B_   16
#define T_   1600
#define D_   512
#define U_   1024
#define G_   4096           // 4*U
#define NWG  256            // 128 per direction, 1 per CU
#define TPB  256
#define KTOT 1536           // D + U
#define APAD 1544           // KTOT + 8 pad (ushort elems)
#define ROWB (APAD*2)       // 3088 bytes per weight row (16B-granule stride 193 mod 8 = 1)

typedef __attribute__((ext_vector_type(8))) __bf16 bf16x8;
typedef __attribute__((ext_vector_type(4))) float  f32x4;
typedef __attribute__((ext_vector_type(8))) unsigned short us8v;

__device__ __forceinline__ unsigned short f2bf(float f) {
  unsigned u = __builtin_bit_cast(unsigned, f);
  u += 0x7FFFu + ((u >> 16) & 1u);          // round-to-nearest-even
  return (unsigned short)(u >> 16);
}
__device__ __forceinline__ bf16x8 cvt8(const float4 a, const float4 b) {
  us8v r;
  r[0]=f2bf(a.x); r[1]=f2bf(a.y); r[2]=f2bf(a.z); r[3]=f2bf(a.w);
  r[4]=f2bf(b.x); r[5]=f2bf(b.y); r[6]=f2bf(b.z); r[7]=f2bf(b.w);
  return __builtin_bit_cast(bf16x8, r);
}
__device__ __forceinline__ float sigm(float x){ return 1.f / (1.f + __expf(-x)); }
__device__ __forceinline__ float tanh_(float x){ return 1.f - 2.f / (__expf(2.f*x) + 1.f); }

extern "C" __global__ void __launch_bounds__(TPB, 1)
bilstm_kernel(const float* __restrict__ x, const int* __restrict__ xlen,
              const float* __restrict__ kf, const float* __restrict__ rkf, const float* __restrict__ bf_,
              const float* __restrict__ kb, const float* __restrict__ rkb, const float* __restrict__ bb_,
              float* __restrict__ out, unsigned* __restrict__ sync_ctr,
              unsigned short* __restrict__ hbuf)
{
  extern __shared__ char smem[];
  char*  Wb     = smem;                       // [32 cols][APAD] ushort, W[col][k] bf16
  float* gates  = (float*)(smem + 32*ROWB);   // [2 khalf][16][32]
  float* bias_s = gates + 1024;               // [32]
  float* c_s    = bias_s + 32;                // [16][8] cell state

  const int tid = threadIdx.x;
  const int wg  = blockIdx.x;
  const int dir = wg >> 7;
  const int u0  = (wg & 127) << 3;

  if (wg == 0 && tid < B_)
    out[(size_t)B_*T_*2*U_ + tid] = (float)xlen[tid];

  const float* Km = dir ? kb  : kf;
  const float* Rm = dir ? rkb : rkf;
  const float* Bv = dir ? bb_ : bf_;

  // one-time: weight slice [1536][32] -> LDS bf16, layout W[col][k]
  for (int i = tid; i < KTOT*32; i += TPB) {
    int k = i >> 5, c = i & 31;
    int gc = ((c >> 3) << 10) + u0 + (c & 7);
    float wv = (k < D_) ? Km[(size_t)k*G_ + gc] : Rm[(size_t)(k-D_)*G_ + gc];
    *(unsigned short*)(Wb + c*ROWB + (k << 1)) = f2bf(wv);
  }
  if (tid < 32)  bias_s[tid] = Bv[((tid >> 3) << 10) + u0 + (tid & 7)];
  if (tid < 128) c_s[tid] = 0.f;
  __syncthreads();

  const int w = tid >> 6, l = tid & 63;
  const int ntile = w & 1, khalf = w >> 1;
  const char* Brow = Wb + (ntile*16 + (l & 15))*ROWB + ((l >> 4) << 4);
  float* gp = gates + khalf*512;
  const int drow0 = (l >> 4) << 2, dcol = ntile*16 + (l & 15);

  unsigned* ctr = sync_ctr + dir*32;          // 128B apart per direction

  // per-lane global A-operand bases (row = l&15, k-offset = (l>>4)*8, khalf K-split)
  const float* xbase = x + (size_t)(l & 15)*T_*D_ + khalf*256 + ((l >> 4) << 3);
  const size_t hlane = (size_t)((l & 15) << 10) + khalf*512 + ((l >> 4) << 3);

  // prologue: x-projection for t=0 into register accumulator
  f32x4 acc = {0.f, 0.f, 0.f, 0.f};
  {
    const int tg0 = dir ? (T_ - 1) : 0;
    const float* xA = xbase + (size_t)tg0 * D_;
    #pragma unroll
    for (int i = 0; i < 8; ++i) {
      float4 lo = *(const float4*)(xA + i*32);
      float4 hi = *(const float4*)(xA + i*32 + 4);
      bf16x8 bv = *(const bf16x8*)(Brow + ((khalf*8 + i) << 6));
      acc = __builtin_amdgcn_mfma_f32_16x16x32_bf16(cvt8(lo, hi), bv, acc, 0, 0, 0);
    }
  }

  for (int t = 0; t < T_; ++t) {
    const int tg = dir ? (T_ - 1 - t) : t;

    if (t > 0) {
      // wait: all WGs in this direction published h_{t-1}
      if (tid == 0) {
        const unsigned tgt = (unsigned)t * 128u;
        long long guard = 0;
        while (__hip_atomic_load(ctr, __ATOMIC_RELAXED, __HIP_MEMORY_SCOPE_AGENT) < tgt) {
          __builtin_amdgcn_s_sleep(1);
          if (++guard > (1LL << 24)) break;
        }
        __builtin_amdgcn_fence(__ATOMIC_ACQUIRE, "agent");
      }
      __syncthreads();

      // recurrent MFMAs: A = h_{t-1} direct from global (double-buffered)
      const unsigned short* hA = hbuf + (((size_t)((t & 1)*2 + dir)) << 14) + hlane;
      #pragma unroll
      for (int i = 0; i < 16; ++i) {
        bf16x8 a  = *(const bf16x8*)(hA + i*32);
        bf16x8 bv = *(const bf16x8*)(Brow + ((16 + khalf*16 + i) << 6));
        acc = __builtin_amdgcn_mfma_f32_16x16x32_bf16(a, bv, acc, 0, 0, 0);
      }
    }

    #pragma unroll
    for (int j = 0; j < 4; ++j) gp[(drow0 + j)*32 + dcol] = acc[j];
    __syncthreads();

    // epilogue: one thread per (batch, unit)
    if (tid < 128) {
      int b = tid >> 3, uo = tid & 7;
      const float* g0 = gates + b*32 + uo;
      float gi = g0[0]  + g0[512] + bias_s[uo];
      float gf = g0[8]  + g0[520] + bias_s[8 + uo];
      float gz = g0[16] + g0[528] + bias_s[16 + uo];
      float go = g0[24] + g0[536] + bias_s[24 + uo];
      float cn = sigm(gf)*c_s[tid] + sigm(gi)*tanh_(gz);
      c_s[tid] = cn;
      float h = sigm(go)*tanh_(cn);
      out[((size_t)b*T_ + tg)*(2*U_) + (dir << 10) + u0 + uo] = h;
      hbuf[(((size_t)(((t & 1) ^ 1)*2 + dir)) << 14) + (b << 10) + u0 + uo] = f2bf(h);
    }
    __syncthreads();   // hbuf stores drained before release; gates safe to reuse

    if (t + 1 < T_) {
      if (tid == 0)
        __hip_atomic_fetch_add(ctr, 1u, __ATOMIC_RELEASE, __HIP_MEMORY_SCOPE_AGENT);

      // x-projection for t+1 in the barrier shadow
      const float* xA = xbase + (size_t)(dir ? (T_ - 2 - t) : (t + 1)) * D_;
      f32x4 nacc = {0.f, 0.f, 0.f, 0.f};
      #pragma unroll
      for (int i = 0; i < 8; ++i) {
        float4 lo = *(const float4*)(xA + i*32);
        float4 hi = *(const float4*)(xA + i*32 + 4);
        bf16x8 bv = *(const bf16x8*)(Brow + ((khalf*8 + i) << 6));
        nacc = __builtin_amdgcn_mfma_f32_16x16x32_bf16(cvt8(lo, hi), bv, nacc, 0, 0, 0);
      }
      acc = nacc;
    }
  }
}

extern "C" void kernel_launch(void* const* d_in, const int* in_sizes, int n_in,
                              void* d_out, int out_size, void* d_ws, size_t ws_size,
                              hipStream_t stream) {
  const float* x   = (const float*)d_in[0];
  const int*   xl  = (const int*)d_in[1];
  const float* kf  = (const float*)d_in[2];
  const float* rkf = (const float*)d_in[3];
  const float* bf_ = (const float*)d_in[4];
  const float* kb  = (const float*)d_in[5];
  const float* rkb = (const float*)d_in[6];
  const float* bb_ = (const float*)d_in[7];
  float* out = (float*)d_out;

  unsigned* ctr = (unsigned*)d_ws;
  unsigned short* hbuf = (unsigned short*)((char*)d_ws + 256);

  hipMemsetAsync(d_ws, 0, 256, stream);   // reset both direction counters (graph-safe)

  const size_t smem = 32*(size_t)ROWB + 1024*4 + 32*4 + 128*4;  // 103,552 B -> 1 WG/CU
  bilstm_kernel<<<NWG, TPB, smem, stream>>>(x, xl, kf, rkf, bf_, kb, rkb, bb_, out, ctr, hbuf);
}

// Round 4
// 12859.166 us; speedup vs baseline: 2.4204x; 1.2241x over previous
//
#include <hip/hip_runtime.h>

#define B_   16
#define T_   1600
#define D_   512
#define U_   1024
#define G_   4096           // 4*U
#define NWG  256            // 128 per direction, 1 per CU
#define TPB  256
#define KTOT 1536           // D + U
#define APAD 1544           // staging pad (ushort elems)
#define ROWB (APAD*2)

typedef __attribute__((ext_vector_type(8))) __bf16 bf16x8;
typedef __attribute__((ext_vector_type(4))) float  f32x4;
typedef __attribute__((ext_vector_type(2))) float  f32x2;
typedef __attribute__((ext_vector_type(8))) unsigned short us8v;
typedef __attribute__((ext_vector_type(2))) unsigned long long u64x2;
typedef unsigned long long u64;

__device__ __forceinline__ unsigned short f2bf(float f) {
  unsigned u = __builtin_bit_cast(unsigned, f);
  u += 0x7FFFu + ((u >> 16) & 1u);
  return (unsigned short)(u >> 16);
}
__device__ __forceinline__ bf16x8 cvt8(const float4 a, const float4 b) {
  us8v r;
  r[0]=f2bf(a.x); r[1]=f2bf(a.y); r[2]=f2bf(a.z); r[3]=f2bf(a.w);
  r[4]=f2bf(b.x); r[5]=f2bf(b.y); r[6]=f2bf(b.z); r[7]=f2bf(b.w);
  return __builtin_bit_cast(bf16x8, r);
}
__device__ __forceinline__ bf16x8 ld_h16(const unsigned short* p) {
  u64x2 t;
  t[0] = __hip_atomic_load((const u64*)p,     __ATOMIC_RELAXED, __HIP_MEMORY_SCOPE_AGENT);
  t[1] = __hip_atomic_load((const u64*)p + 1, __ATOMIC_RELAXED, __HIP_MEMORY_SCOPE_AGENT);
  return __builtin_bit_cast(bf16x8, t);
}
__device__ __forceinline__ float sigm(float x){ return 1.f / (1.f + __expf(-x)); }
__device__ __forceinline__ float tanh_(float x){ return 1.f - 2.f / (__expf(2.f*x) + 1.f); }

extern "C" __global__ void __launch_bounds__(TPB, 1)
bilstm_kernel(const float* __restrict__ x, const int* __restrict__ xlen,
              const float* __restrict__ kf, const float* __restrict__ rkf, const float* __restrict__ bf_,
              const float* __restrict__ kb, const float* __restrict__ rkb, const float* __restrict__ bb_,
              float* __restrict__ out, unsigned* __restrict__ sync_ctr,
              unsigned short* __restrict__ hbuf)
{
  extern __shared__ char smem[];

  const int tid = threadIdx.x;
  const int wg  = blockIdx.x;
  const int dir = wg >> 7;
  const int u0  = (wg & 127) << 3;

  if (wg == 0 && tid < B_)
    out[(size_t)B_*T_*2*U_ + tid] = (float)xlen[tid];

  const float* Km = dir ? kb  : kf;
  const float* Rm = dir ? rkb : rkf;
  const float* Bv = dir ? bb_ : bf_;

  const int w = tid >> 6, l = tid & 63;
  const int ntile = w & 1, khalf = w >> 1;

  // ---- phase 1: stage weight slice [1536][32] -> LDS bf16 (coalesced) ----
  {
    char* Wb = smem;
    for (int i = tid; i < KTOT*32; i += TPB) {
      int k = i >> 5, c = i & 31;
      int gc = ((c >> 3) << 10) + u0 + (c & 7);
      float wv = (k < D_) ? Km[(size_t)k*G_ + gc] : Rm[(size_t)(k-D_)*G_ + gc];
      *(unsigned short*)(Wb + c*ROWB + (k << 1)) = f2bf(wv);
    }
  }
  __syncthreads();

  // ---- phase 2: each thread pulls its 24 B-fragments into VGPRs ----
  bf16x8 wx[8], wh[16];
  {
    const char* Brow = smem + (ntile*16 + (l & 15))*ROWB + ((l >> 4) << 4);
    #pragma unroll
    for (int i = 0; i < 8; ++i)  wx[i] = *(const bf16x8*)(Brow + ((khalf*8 + i) << 6));
    #pragma unroll
    for (int i = 0; i < 16; ++i) wh[i] = *(const bf16x8*)(Brow + ((16 + khalf*16 + i) << 6));
  }
  __syncthreads();   // weight LDS now dead; reuse as gates buffer

  float* gates = (float*)smem;            // [2 khalf][16 b][32 col]
  float* gp    = gates + khalf*512;
  const int drow0 = (l >> 4) << 2, dcol = ntile*16 + (l & 15);

  // epilogue-thread state (tid < 64): 2 units each, bias + cell in registers
  const int eb = tid >> 2, eup = (tid & 3) << 1;
  float bi0=0, bi1=0, bff0=0, bff1=0, bz0=0, bz1=0, bo0=0, bo1=0, c0=0, c1=0;
  if (tid < 64) {
    bi0 = Bv[u0+eup];        bi1 = Bv[u0+eup+1];
    bff0= Bv[1024+u0+eup];   bff1= Bv[1024+u0+eup+1];
    bz0 = Bv[2048+u0+eup];   bz1 = Bv[2048+u0+eup+1];
    bo0 = Bv[3072+u0+eup];   bo1 = Bv[3072+u0+eup+1];
  }

  unsigned* ctr = sync_ctr + dir*32;      // 128B apart per direction

  const float* xbase = x + (size_t)(l & 15)*T_*D_ + khalf*256 + ((l >> 4) << 3);
  const size_t hlane = (size_t)((l & 15) << 10) + khalf*512 + ((l >> 4) << 3);

  // prologue: x-projection for t=0
  f32x4 acc = {0.f, 0.f, 0.f, 0.f};
  {
    const float* xA = xbase + (size_t)(dir ? (T_ - 1) : 0) * D_;
    #pragma unroll
    for (int i = 0; i < 8; ++i) {
      float4 lo = *(const float4*)(xA + i*32);
      float4 hi = *(const float4*)(xA + i*32 + 4);
      acc = __builtin_amdgcn_mfma_f32_16x16x32_bf16(cvt8(lo, hi), wx[i], acc, 0, 0, 0);
    }
  }

  for (int t = 0; t < T_; ++t) {
    const int tg = dir ? (T_ - 1 - t) : t;

    if (t > 0) {
      // poll (all lanes, per-wave; no workgroup barrier needed here)
      const unsigned tgt = (unsigned)t * 128u;
      long long guard = 0;
      while (__hip_atomic_load(ctr, __ATOMIC_RELAXED, __HIP_MEMORY_SCOPE_AGENT) < tgt) {
        __builtin_amdgcn_s_sleep(1);
        if (++guard > (1LL << 22)) break;
      }
      __builtin_amdgcn_fence(__ATOMIC_ACQUIRE, "workgroup");  // order h-loads after poll (waitcnt only)

      // recurrent MFMAs, A = h_{t-1} via LLC-bypass loads; 2 accs break dep chain
      const unsigned short* hA = hbuf + (((size_t)((t & 1)*2 + dir)) << 14) + hlane;
      f32x4 acc2 = {0.f, 0.f, 0.f, 0.f};
      #pragma unroll
      for (int i = 0; i < 16; i += 2) {
        acc  = __builtin_amdgcn_mfma_f32_16x16x32_bf16(ld_h16(hA + i*32),       wh[i],   acc,  0, 0, 0);
        acc2 = __builtin_amdgcn_mfma_f32_16x16x32_bf16(ld_h16(hA + (i+1)*32),   wh[i+1], acc2, 0, 0, 0);
      }
      acc[0]+=acc2[0]; acc[1]+=acc2[1]; acc[2]+=acc2[2]; acc[3]+=acc2[3];
    }

    #pragma unroll
    for (int j = 0; j < 4; ++j) gp[(drow0 + j)*32 + dcol] = acc[j];
    __syncthreads();

    // epilogue: 64 threads, 2 units each
    if (tid < 64) {
      const float* g0 = gates + eb*32 + eup;
      float gi0 = g0[0]  + g0[512] + bi0,  gi1 = g0[1]  + g0[513] + bi1;
      float gf0 = g0[8]  + g0[520] + bff0, gf1 = g0[9]  + g0[521] + bff1;
      float gz0 = g0[16] + g0[528] + bz0,  gz1 = g0[17] + g0[529] + bz1;
      float go0 = g0[24] + g0[536] + bo0,  go1 = g0[25] + g0[537] + bo1;
      c0 = sigm(gf0)*c0 + sigm(gi0)*tanh_(gz0);
      c1 = sigm(gf1)*c1 + sigm(gi1)*tanh_(gz1);
      float h0 = sigm(go0)*tanh_(c0);
      float h1 = sigm(go1)*tanh_(c1);
      f32x2 ho; ho.x = h0; ho.y = h1;
      __builtin_nontemporal_store(ho, (f32x2*)(out + ((size_t)eb*T_ + tg)*(2*U_) + (dir << 10) + u0 + eup));
      unsigned hp = ((unsigned)f2bf(h1) << 16) | (unsigned)f2bf(h0);
      unsigned* hdst = (unsigned*)(hbuf + (((size_t)(((t & 1) ^ 1)*2 + dir)) << 14) + (eb << 10) + u0 + eup);
      __hip_atomic_store(hdst, hp, __ATOMIC_RELAXED, __HIP_MEMORY_SCOPE_AGENT);
    }
    __syncthreads();   // compiler emits s_waitcnt vmcnt(0) before s_barrier -> h stores are at LLC

    if (t + 1 < T_) {
      if (tid == 0)
        __hip_atomic_fetch_add(ctr, 1u, __ATOMIC_RELAXED, __HIP_MEMORY_SCOPE_AGENT);

      // x-projection for t+1 in the barrier shadow
      const float* xA = xbase + (size_t)(dir ? (T_ - 2 - t) : (t + 1)) * D_;
      f32x4 nacc = {0.f, 0.f, 0.f, 0.f};
      #pragma unroll
      for (int i = 0; i < 8; ++i) {
        float4 lo = *(const float4*)(xA + i*32);
        float4 hi = *(const float4*)(xA + i*32 + 4);
        nacc = __builtin_amdgcn_mfma_f32_16x16x32_bf16(cvt8(lo, hi), wx[i], nacc, 0, 0, 0);
      }
      acc = nacc;
    }
  }
}

extern "C" void kernel_launch(void* const* d_in, const int* in_sizes, int n_in,
                              void* d_out, int out_size, void* d_ws, size_t ws_size,
                              hipStream_t stream) {
  const float* x   = (const float*)d_in[0];
  const int*   xl  = (const int*)d_in[1];
  const float* kf  = (const float*)d_in[2];
  const float* rkf = (const float*)d_in[3];
  const float* bf_ = (const float*)d_in[4];
  const float* kb  = (const float*)d_in[5];
  const float* rkb = (const float*)d_in[6];
  const float* bb_ = (const float*)d_in[7];
  float* out = (float*)d_out;

  unsigned* ctr = (unsigned*)d_ws;
  unsigned short* hbuf = (unsigned short*)((char*)d_ws + 256);

  (void)hipMemsetAsync(d_ws, 0, 256, stream);

  const size_t smem = 32*(size_t)ROWB;   // 98,816 B (staging); runtime uses first 4 KB
  bilstm_kernel<<<NWG, TPB, smem, stream>>>(x, xl, kf, rkf, bf_, kb, rkb, bb_, out, ctr, hbuf);
}

// Round 5
// 12781.635 us; speedup vs baseline: 2.4351x; 1.0061x over previous
//
#include <hip/hip_runtime.h>

#define B_   16
#define T_   1600
#define D_   512
#define U_   1024
#define G_   4096           // 4*U
#define NWG  256            // 128 per direction, 1 per CU
#define TPB  256
#define KTOT 1536           // D + U
#define APAD 1544           // staging pad (ushort elems)
#define ROWB (APAD*2)

typedef __attribute__((ext_vector_type(8))) __bf16 bf16x8;
typedef __attribute__((ext_vector_type(4))) float  f32x4;
typedef __attribute__((ext_vector_type(2))) float  f32x2;
typedef __attribute__((ext_vector_type(8))) unsigned short us8v;
typedef __attribute__((ext_vector_type(2))) unsigned long long u64x2;
typedef unsigned long long u64;

__device__ __forceinline__ unsigned short f2bf(float f) {
  unsigned u = __builtin_bit_cast(unsigned, f);
  u += 0x7FFFu + ((u >> 16) & 1u);
  return (unsigned short)(u >> 16);
}
__device__ __forceinline__ bf16x8 cvt8(const float4 a, const float4 b) {
  us8v r;
  r[0]=f2bf(a.x); r[1]=f2bf(a.y); r[2]=f2bf(a.z); r[3]=f2bf(a.w);
  r[4]=f2bf(b.x); r[5]=f2bf(b.y); r[6]=f2bf(b.z); r[7]=f2bf(b.w);
  return __builtin_bit_cast(bf16x8, r);
}
__device__ __forceinline__ bf16x8 ld_h16(const unsigned short* p) {
  u64x2 t;
  t[0] = __hip_atomic_load((const u64*)p,     __ATOMIC_RELAXED, __HIP_MEMORY_SCOPE_AGENT);
  t[1] = __hip_atomic_load((const u64*)p + 1, __ATOMIC_RELAXED, __HIP_MEMORY_SCOPE_AGENT);
  return __builtin_bit_cast(bf16x8, t);
}
__device__ __forceinline__ float sigm(float x){ return 1.f / (1.f + __expf(-x)); }
__device__ __forceinline__ float tanh_(float x){ return 1.f - 2.f / (__expf(2.f*x) + 1.f); }

extern "C" __global__ void __launch_bounds__(TPB, 1)
bilstm_kernel(const float* __restrict__ x, const int* __restrict__ xlen,
              const float* __restrict__ kf, const float* __restrict__ rkf, const float* __restrict__ bf_,
              const float* __restrict__ kb, const float* __restrict__ rkb, const float* __restrict__ bb_,
              float* __restrict__ out, unsigned* __restrict__ flags,
              unsigned short* __restrict__ hbuf)
{
  extern __shared__ char smem[];

  const int tid = threadIdx.x;
  const int wg  = blockIdx.x;
  const int dir = wg >> 7;
  const int slot = wg & 127;
  const int u0  = slot << 3;

  if (wg == 0 && tid < B_)
    out[(size_t)B_*T_*2*U_ + tid] = (float)xlen[tid];

  const float* Km = dir ? kb  : kf;
  const float* Rm = dir ? rkb : rkf;
  const float* Bv = dir ? bb_ : bf_;

  const int w = tid >> 6, l = tid & 63;
  const int ntile = w & 1, khalf = w >> 1;

  // ---- phase 1: stage weight slice [1536][32] -> LDS bf16 (coalesced) ----
  {
    char* Wb = smem;
    for (int i = tid; i < KTOT*32; i += TPB) {
      int k = i >> 5, c = i & 31;
      int gc = ((c >> 3) << 10) + u0 + (c & 7);
      float wv = (k < D_) ? Km[(size_t)k*G_ + gc] : Rm[(size_t)(k-D_)*G_ + gc];
      *(unsigned short*)(Wb + c*ROWB + (k << 1)) = f2bf(wv);
    }
  }
  __syncthreads();

  // ---- phase 2: each thread pulls its 24 B-fragments into VGPRs ----
  bf16x8 wx[8], wh[16];
  {
    const char* Brow = smem + (ntile*16 + (l & 15))*ROWB + ((l >> 4) << 4);
    #pragma unroll
    for (int i = 0; i < 8; ++i)  wx[i] = *(const bf16x8*)(Brow + ((khalf*8 + i) << 6));
    #pragma unroll
    for (int i = 0; i < 16; ++i) wh[i] = *(const bf16x8*)(Brow + ((16 + khalf*16 + i) << 6));
  }
  __syncthreads();   // weight LDS now dead; reuse as gates buffer

  float* gates = (float*)smem;            // [2 khalf][16 b][32 col]
  float* gp    = gates + khalf*512;
  const int drow0 = (l >> 4) << 2, dcol = ntile*16 + (l & 15);

  // epilogue-thread state (wave 0 only): 2 units each, bias + cell in registers
  const int eb = tid >> 2, eup = (tid & 3) << 1;
  float bi0=0, bi1=0, bff0=0, bff1=0, bz0=0, bz1=0, bo0=0, bo1=0, c0=0, c1=0;
  if (tid < 64) {
    bi0 = Bv[u0+eup];        bi1 = Bv[u0+eup+1];
    bff0= Bv[1024+u0+eup];   bff1= Bv[1024+u0+eup+1];
    bz0 = Bv[2048+u0+eup];   bz1 = Bv[2048+u0+eup+1];
    bo0 = Bv[3072+u0+eup];   bo1 = Bv[3072+u0+eup+1];
  }

  unsigned* myflags = flags + dir*128;    // 512B per direction, 512B apart

  const float* xbase = x + (size_t)(l & 15)*T_*D_ + khalf*256 + ((l >> 4) << 3);
  const size_t hlane = (size_t)((l & 15) << 10) + khalf*512 + ((l >> 4) << 3);

  // prologue: x-projection for t=0
  f32x4 acc = {0.f, 0.f, 0.f, 0.f};
  {
    const float* xA = xbase + (size_t)(dir ? (T_ - 1) : 0) * D_;
    #pragma unroll
    for (int i = 0; i < 8; ++i) {
      float4 lo = *(const float4*)(xA + i*32);
      float4 hi = *(const float4*)(xA + i*32 + 4);
      acc = __builtin_amdgcn_mfma_f32_16x16x32_bf16(cvt8(lo, hi), wx[i], acc, 0, 0, 0);
    }
  }

  for (int t = 0; t < T_; ++t) {
    const int tg = dir ? (T_ - 1 - t) : t;

    if (t > 0) {
      // wave 0 polls the 128 producer flags (read-only, 4 cache lines, no RMW)
      if (tid < 64) {
        const unsigned tgt = (unsigned)t;
        long long guard = 0;
        for (;;) {
          unsigned a = __hip_atomic_load(myflags + l,      __ATOMIC_RELAXED, __HIP_MEMORY_SCOPE_AGENT);
          unsigned b = __hip_atomic_load(myflags + 64 + l, __ATOMIC_RELAXED, __HIP_MEMORY_SCOPE_AGENT);
          if (__all((a >= tgt) && (b >= tgt))) break;
          __builtin_amdgcn_s_sleep(2);
          if (++guard > (1LL << 22)) break;
        }
      }
      __syncthreads();   // releases waves 1-3; orders gates-buffer rewrite after epilogue reads

      // recurrent MFMAs, A = h_{t-1} via LLC-bypass loads; 2 accs break dep chain
      const unsigned short* hA = hbuf + (((size_t)((t & 1)*2 + dir)) << 14) + hlane;
      f32x4 acc2 = {0.f, 0.f, 0.f, 0.f};
      #pragma unroll
      for (int i = 0; i < 16; i += 2) {
        acc  = __builtin_amdgcn_mfma_f32_16x16x32_bf16(ld_h16(hA + i*32),     wh[i],   acc,  0, 0, 0);
        acc2 = __builtin_amdgcn_mfma_f32_16x16x32_bf16(ld_h16(hA + (i+1)*32), wh[i+1], acc2, 0, 0, 0);
      }
      acc[0]+=acc2[0]; acc[1]+=acc2[1]; acc[2]+=acc2[2]; acc[3]+=acc2[3];
    }

    #pragma unroll
    for (int j = 0; j < 4; ++j) gp[(drow0 + j)*32 + dcol] = acc[j];
    __syncthreads();

    // epilogue: wave 0, 2 units per lane; publish h then flag (wave-local ordering)
    if (tid < 64) {
      const float* g0 = gates + eb*32 + eup;
      float gi0 = g0[0]  + g0[512] + bi0,  gi1 = g0[1]  + g0[513] + bi1;
      float gf0 = g0[8]  + g0[520] + bff0, gf1 = g0[9]  + g0[521] + bff1;
      float gz0 = g0[16] + g0[528] + bz0,  gz1 = g0[17] + g0[529] + bz1;
      float go0 = g0[24] + g0[536] + bo0,  go1 = g0[25] + g0[537] + bo1;
      c0 = sigm(gf0)*c0 + sigm(gi0)*tanh_(gz0);
      c1 = sigm(gf1)*c1 + sigm(gi1)*tanh_(gz1);
      float h0 = sigm(go0)*tanh_(c0);
      float h1 = sigm(go1)*tanh_(c1);
      f32x2 ho; ho.x = h0; ho.y = h1;
      __builtin_nontemporal_store(ho, (f32x2*)(out + ((size_t)eb*T_ + tg)*(2*U_) + (dir << 10) + u0 + eup));
      unsigned hp = ((unsigned)f2bf(h1) << 16) | (unsigned)f2bf(h0);
      unsigned* hdst = (unsigned*)(hbuf + (((size_t)(((t & 1) ^ 1)*2 + dir)) << 14) + (eb << 10) + u0 + eup);
      __hip_atomic_store(hdst, hp, __ATOMIC_RELAXED, __HIP_MEMORY_SCOPE_AGENT);
      asm volatile("s_waitcnt vmcnt(0)" ::: "memory");   // h stores at LLC before flag
      if (tid == 0)
        __hip_atomic_store(myflags + slot, (unsigned)(t + 1), __ATOMIC_RELAXED, __HIP_MEMORY_SCOPE_AGENT);
    }

    if (t + 1 < T_) {
      // x-projection for t+1 in the flag-propagation shadow (all waves)
      const float* xA = xbase + (size_t)(dir ? (T_ - 2 - t) : (t + 1)) * D_;
      f32x4 nacc = {0.f, 0.f, 0.f, 0.f};
      #pragma unroll
      for (int i = 0; i < 8; ++i) {
        float4 lo = *(const float4*)(xA + i*32);
        float4 hi = *(const float4*)(xA + i*32 + 4);
        nacc = __builtin_amdgcn_mfma_f32_16x16x32_bf16(cvt8(lo, hi), wx[i], nacc, 0, 0, 0);
      }
      acc = nacc;
    }
  }
}

extern "C" void kernel_launch(void* const* d_in, const int* in_sizes, int n_in,
                              void* d_out, int out_size, void* d_ws, size_t ws_size,
                              hipStream_t stream) {
  const float* x   = (const float*)d_in[0];
  const int*   xl  = (const int*)d_in[1];
  const float* kf  = (const float*)d_in[2];
  const float* rkf = (const float*)d_in[3];
  const float* bf_ = (const float*)d_in[4];
  const float* kb  = (const float*)d_in[5];
  const float* rkb = (const float*)d_in[6];
  const float* bb_ = (const float*)d_in[7];
  float* out = (float*)d_out;

  unsigned* flags = (unsigned*)d_ws;                              // 2 x 128 u32 = 1 KB
  unsigned short* hbuf = (unsigned short*)((char*)d_ws + 1024);   // 4 x 32 KB double buffers

  (void)hipMemsetAsync(d_ws, 0, 1024, stream);    // reset flags every launch (graph-safe)

  const size_t smem = 32*(size_t)ROWB;   // 98,816 B (staging); runtime uses first 4 KB
  bilstm_kernel<<<NWG, TPB, smem, stream>>>(x, xl, kf, rkf, bf_, kb, rkb, bb_, out, flags, hbuf);
}

// Round 6
// 6036.863 us; speedup vs baseline: 5.1557x; 2.1173x over previous
//
#include <hip/hip_runtime.h>

#define B_   16
#define T_   1600
#define D_   512
#define U_   1024
#define G_   4096           // 4*U
#define NWG  256            // 128 per direction, 1 per CU
#define TPB  256
#define KTOT 1536           // D + U
#define APAD 1544           // weight staging pad (ushort elems)
#define ROWB (APAD*2)

typedef __attribute__((ext_vector_type(8))) __bf16 bf16x8;
typedef __attribute__((ext_vector_type(4))) float  f32x4;
typedef __attribute__((ext_vector_type(2))) float  f32x2;
typedef __attribute__((ext_vector_type(8))) unsigned short us8v;
typedef unsigned long long u64;

__device__ __forceinline__ unsigned short f2bf(float f) {
  unsigned u = __builtin_bit_cast(unsigned, f);
  u += 0x7FFFu + ((u >> 16) & 1u);
  return (unsigned short)(u >> 16);
}
__device__ __forceinline__ bf16x8 cvt8(const float4 a, const float4 b) {
  us8v r;
  r[0]=f2bf(a.x); r[1]=f2bf(a.y); r[2]=f2bf(a.z); r[3]=f2bf(a.w);
  r[4]=f2bf(b.x); r[5]=f2bf(b.y); r[6]=f2bf(b.z); r[7]=f2bf(b.w);
  return __builtin_bit_cast(bf16x8, r);
}
__device__ __forceinline__ float sigm(float x){ return 1.f / (1.f + __expf(-x)); }
__device__ __forceinline__ float tanh_(float x){ return 1.f - 2.f / (__expf(2.f*x) + 1.f); }

extern "C" __global__ void __launch_bounds__(TPB, 1)
bilstm_kernel(const float* __restrict__ x, const int* __restrict__ xlen,
              const float* __restrict__ kf, const float* __restrict__ rkf, const float* __restrict__ bf_,
              const float* __restrict__ kb, const float* __restrict__ rkb, const float* __restrict__ bb_,
              float* __restrict__ out, unsigned* __restrict__ flags,
              unsigned short* __restrict__ hbuf)
{
  extern __shared__ char smem[];

  const int tid = threadIdx.x;
  const int wg  = blockIdx.x;
  const int dir = wg >> 7;
  const int slot = wg & 127;
  const int u0  = slot << 3;

  if (wg == 0 && tid < B_)
    out[(size_t)B_*T_*2*U_ + tid] = (float)xlen[tid];

  const float* Km = dir ? kb  : kf;
  const float* Rm = dir ? rkb : rkf;
  const float* Bv = dir ? bb_ : bf_;

  const int w = tid >> 6, l = tid & 63;
  const int ntile = w & 1, khalf = w >> 1;

  // ---- phase 1: stage weight slice [1536][32] -> LDS bf16 (coalesced) ----
  {
    char* Wb = smem;
    for (int i = tid; i < KTOT*32; i += TPB) {
      int k = i >> 5, c = i & 31;
      int gc = ((c >> 3) << 10) + u0 + (c & 7);
      float wv = (k < D_) ? Km[(size_t)k*G_ + gc] : Rm[(size_t)(k-D_)*G_ + gc];
      *(unsigned short*)(Wb + c*ROWB + (k << 1)) = f2bf(wv);
    }
  }
  __syncthreads();

  // ---- phase 2: each thread pulls its 24 B-fragments into VGPRs/AGPRs ----
  bf16x8 wx[8], wh[16];
  {
    const char* Brow = smem + (ntile*16 + (l & 15))*ROWB + ((l >> 4) << 4);
    #pragma unroll
    for (int i = 0; i < 8; ++i)  wx[i] = *(const bf16x8*)(Brow + ((khalf*8 + i) << 6));
    #pragma unroll
    for (int i = 0; i < 16; ++i) wh[i] = *(const bf16x8*)(Brow + ((16 + khalf*16 + i) << 6));
  }
  __syncthreads();   // weight LDS dead; reuse: gates @0 (4KB), h-stage @4096 (32KB)

  float* gates = (float*)smem;            // [2 khalf][16 b][32 col]
  char*  hst   = smem + 4096;             // [16 b][2048 B] XOR-swizzled bf16 h
  float* gp    = gates + khalf*512;
  const int drow0 = (l >> 4) << 2, dcol = ntile*16 + (l & 15);

  // epilogue-thread state (wave 0 only): 2 units each, bias + cell in registers
  const int eb = tid >> 2, eup = (tid & 3) << 1;
  float bi0=0, bi1=0, bff0=0, bff1=0, bz0=0, bz1=0, bo0=0, bo1=0, c0=0, c1=0;
  if (tid < 64) {
    bi0 = Bv[u0+eup];        bi1 = Bv[u0+eup+1];
    bff0= Bv[1024+u0+eup];   bff1= Bv[1024+u0+eup+1];
    bz0 = Bv[2048+u0+eup];   bz1 = Bv[2048+u0+eup+1];
    bo0 = Bv[3072+u0+eup];   bo1 = Bv[3072+u0+eup+1];
  }

  unsigned* myflags = flags + dir*128;

  const float* xbase = x + (size_t)(l & 15)*T_*D_ + khalf*256 + ((l >> 4) << 3);

  // A-frag LDS read base: row = l&15, k-byte base = 2*(khalf*512 + (l>>4)*8)
  const char* hrow  = hst + (l & 15)*2048;
  const int   kbase = (khalf*512 + ((l >> 4) << 3)) << 1;
  const int   swz   = ((l & 15) & 7) << 4;

  // prologue: x-projection for t=0
  f32x4 acc = {0.f, 0.f, 0.f, 0.f};
  {
    const float* xA = xbase + (size_t)(dir ? (T_ - 1) : 0) * D_;
    #pragma unroll
    for (int i = 0; i < 8; ++i) {
      float4 lo = *(const float4*)(xA + i*32);
      float4 hi = *(const float4*)(xA + i*32 + 4);
      acc = __builtin_amdgcn_mfma_f32_16x16x32_bf16(cvt8(lo, hi), wx[i], acc, 0, 0, 0);
    }
  }

  for (int t = 0; t < T_; ++t) {
    const int tg = dir ? (T_ - 1 - t) : t;

    if (t > 0) {
      // wave 0 polls the 128 producer flags (read-only)
      if (tid < 64) {
        const unsigned tgt = (unsigned)t;
        long long guard = 0;
        for (;;) {
          unsigned a = __hip_atomic_load(myflags + l,      __ATOMIC_RELAXED, __HIP_MEMORY_SCOPE_AGENT);
          unsigned b = __hip_atomic_load(myflags + 64 + l, __ATOMIC_RELAXED, __HIP_MEMORY_SCOPE_AGENT);
          if (__all((a >= tgt) && (b >= tgt))) break;
          __builtin_amdgcn_s_sleep(1);
          if (++guard > (1LL << 22)) break;
        }
      }
      __syncthreads();   // S1: flag confirmed for all waves; gates(t-1) reads done

      // cooperative coalesced h load -> LDS (XOR-swizzled rows), sc0sc1 coherent
      {
        const u64* hsrc = (const u64*)(hbuf + (((size_t)((t & 1)*2 + dir)) << 14));
        u64 tmp[16];
        #pragma unroll
        for (int j = 0; j < 16; ++j)
          tmp[j] = __hip_atomic_load(hsrc + tid + j*256, __ATOMIC_RELAXED, __HIP_MEMORY_SCOPE_AGENT);
        #pragma unroll
        for (int j = 0; j < 16; ++j)
          *(u64*)(hst + j*2048 + ((tid << 3) ^ ((j & 7) << 4))) = tmp[j];
      }
      __syncthreads();   // S2: h-stage complete

      // recurrent MFMAs from LDS; 2 accumulators break the dep chain
      f32x4 acc2 = {0.f, 0.f, 0.f, 0.f};
      #pragma unroll
      for (int i = 0; i < 16; i += 2) {
        bf16x8 a0 = *(const bf16x8*)(hrow + ((kbase + i*64)       ^ swz));
        bf16x8 a1 = *(const bf16x8*)(hrow + ((kbase + (i+1)*64)   ^ swz));
        acc  = __builtin_amdgcn_mfma_f32_16x16x32_bf16(a0, wh[i],   acc,  0, 0, 0);
        acc2 = __builtin_amdgcn_mfma_f32_16x16x32_bf16(a1, wh[i+1], acc2, 0, 0, 0);
      }
      acc[0]+=acc2[0]; acc[1]+=acc2[1]; acc[2]+=acc2[2]; acc[3]+=acc2[3];
    }

    #pragma unroll
    for (int j = 0; j < 4; ++j) gp[(drow0 + j)*32 + dcol] = acc[j];
    __syncthreads();   // S3: gates ready; h-stage reads done

    // epilogue: wave 0, 2 units per lane; publish h then flag (wave-local order)
    if (tid < 64) {
      const float* g0 = gates + eb*32 + eup;
      float gi0 = g0[0]  + g0[512] + bi0,  gi1 = g0[1]  + g0[513] + bi1;
      float gf0 = g0[8]  + g0[520] + bff0, gf1 = g0[9]  + g0[521] + bff1;
      float gz0 = g0[16] + g0[528] + bz0,  gz1 = g0[17] + g0[529] + bz1;
      float go0 = g0[24] + g0[536] + bo0,  go1 = g0[25] + g0[537] + bo1;
      c0 = sigm(gf0)*c0 + sigm(gi0)*tanh_(gz0);
      c1 = sigm(gf1)*c1 + sigm(gi1)*tanh_(gz1);
      float h0 = sigm(go0)*tanh_(c0);
      float h1 = sigm(go1)*tanh_(c1);
      f32x2 ho; ho.x = h0; ho.y = h1;
      __builtin_nontemporal_store(ho, (f32x2*)(out + ((size_t)eb*T_ + tg)*(2*U_) + (dir << 10) + u0 + eup));
      unsigned hp = ((unsigned)f2bf(h1) << 16) | (unsigned)f2bf(h0);
      unsigned* hdst = (unsigned*)(hbuf + (((size_t)(((t & 1) ^ 1)*2 + dir)) << 14) + (eb << 10) + u0 + eup);
      __hip_atomic_store(hdst, hp, __ATOMIC_RELAXED, __HIP_MEMORY_SCOPE_AGENT);
      asm volatile("s_waitcnt vmcnt(0)" ::: "memory");   // h at LLC before flag
      if (tid == 0)
        __hip_atomic_store(myflags + slot, (unsigned)(t + 1), __ATOMIC_RELAXED, __HIP_MEMORY_SCOPE_AGENT);
    }

    if (t + 1 < T_) {
      // x-projection for t+1 in the flag-propagation shadow (all waves)
      const float* xA = xbase + (size_t)(dir ? (T_ - 2 - t) : (t + 1)) * D_;
      f32x4 nacc = {0.f, 0.f, 0.f, 0.f};
      #pragma unroll
      for (int i = 0; i < 8; ++i) {
        float4 lo = *(const float4*)(xA + i*32);
        float4 hi = *(const float4*)(xA + i*32 + 4);
        nacc = __builtin_amdgcn_mfma_f32_16x16x32_bf16(cvt8(lo, hi), wx[i], nacc, 0, 0, 0);
      }
      acc = nacc;
    }
  }
}

extern "C" void kernel_launch(void* const* d_in, const int* in_sizes, int n_in,
                              void* d_out, int out_size, void* d_ws, size_t ws_size,
                              hipStream_t stream) {
  const float* x   = (const float*)d_in[0];
  const int*   xl  = (const int*)d_in[1];
  const float* kf  = (const float*)d_in[2];
  const float* rkf = (const float*)d_in[3];
  const float* bf_ = (const float*)d_in[4];
  const float* kb  = (const float*)d_in[5];
  const float* rkb = (const float*)d_in[6];
  const float* bb_ = (const float*)d_in[7];
  float* out = (float*)d_out;

  unsigned* flags = (unsigned*)d_ws;                              // 2 x 128 u32
  unsigned short* hbuf = (unsigned short*)((char*)d_ws + 1024);   // 4 x 32 KB double buffers

  (void)hipMemsetAsync(d_ws, 0, 1024, stream);    // reset flags every launch (graph-safe)

  const size_t smem = 32*(size_t)ROWB;   // 98,816 B (weight staging); runtime uses 36,864 B
  bilstm_kernel<<<NWG, TPB, smem, stream>>>(x, xl, kf, rkf, bf_, kb, rkb, bb_, out, flags, hbuf);
}